// Round 6
// baseline (220.275 us; speedup 1.0000x reference)
//
#include <hip/hip_runtime.h>

// GraphConvolution: out = input @ W_self + (adj @ input) @ W_agg
//                       = adj @ (input @ W_agg) + input @ W_self   [associativity]
// Heavy op: adj(16384x16384 fp32, 1.07GB) @ Y(16384x128 bf16) -> memory-bound.
//
// main r6: BM=64 BN=128. A: BK_A=256, reg-staged fp32->bf16 (1KB/row DRAM reads,
//   cvt once, out of main loop), dbuf 2x32KB. B: BK_B=128, global_load_lds,
//   TRIPLE-buffered 3x32KB -> ONE barrier per sub-tile (128 total, was 256).
//   LDS = 160KB exactly. Counted vmcnt {12,8,4}, never 0 in loop.
// prep (r5, unchanged): MFMA, Z fp32 + Y bf16 pre-tiled.
//
// ws: [0,4MB) Yt bf16 pre-tiled in 128-row tiles: elem = H*16384 + (ch*128+n)*8 + kin,
//     H=m>>7, ch=(m>>3)&15, kin=m&7.   [4MB,12MB) Z fp32 row-major.

#define NROWS 16384
#define FDIM  128
#define NTA   64           // A iterations (BK_A=256); 2 B sub-tiles (BK_B=128) each

typedef __attribute__((ext_vector_type(4))) float f32x4;
typedef __attribute__((ext_vector_type(8))) short short8;
typedef __attribute__((ext_vector_type(8))) __bf16 bf16x8;
typedef __attribute__((ext_vector_type(4))) unsigned short ushort4v;

static __device__ __forceinline__ unsigned short f2bf(float f) {
  union { __bf16 b; unsigned short u; } cvt;
  cvt.b = (__bf16)f;   // RNE fptrunc
  return cvt.u;
}

// ---------------------------------------------------------------------------
// Kernel 1 (MFMA): Z = input @ W_self (fp32), Y = input @ W_agg (bf16, tiled).
// ---------------------------------------------------------------------------
__global__ __launch_bounds__(256, 2)
void gcn_prep(const float* __restrict__ input, const float* __restrict__ weight,
              unsigned short* __restrict__ Yt, float* __restrict__ Z)
{
  __shared__ __align__(16) unsigned short inA[8192];    // 16KB
  __shared__ __align__(16) unsigned short Wt[32768];    // 64KB
  char* inA_c = (char*)inA;
  char* Wt_c  = (char*)Wt;

  const int tid  = threadIdx.x;
  const int lane = tid & 63;
  const int wv   = tid >> 6;     // 0..3
  const int m0g  = blockIdx.x * 64;

#pragma unroll
  for (int p = 0; p < 8; ++p) {
    const int idx4 = tid + p * 256;
    const int row  = idx4 >> 5;
    const int k0   = (idx4 & 31) * 4;
    const f32x4 v  = *(const f32x4*)(input + (size_t)(m0g + row) * FDIM + k0);
    ushort4v u;
#pragma unroll
    for (int i = 0; i < 4; ++i) u[i] = f2bf(v[i]);
    *(ushort4v*)(inA_c + row * 256 + ((k0 * 2) ^ ((row & 7) << 4))) = u;
  }
#pragma unroll
  for (int p = 0; p < 32; ++p) {
    const int e4   = tid + p * 256;
    const int krow = e4 >> 5;
    const int n0   = (e4 & 31) * 4;
    const f32x4 v  = *(const f32x4*)(weight + (size_t)krow * FDIM + n0);
    const int k  = krow & 127;
    const int nb = (krow >> 7) * 128;
#pragma unroll
    for (int i = 0; i < 4; ++i) {
      const int n = nb + n0 + i;
      *(unsigned short*)(Wt_c + n * 256 + ((k * 2) ^ ((n & 7) << 4))) = f2bf(v[i]);
    }
  }
  __syncthreads();

  const int rlo  = lane & 15;
  const int kgrp = lane >> 4;
  const int arow = wv * 16 + rlo;

  f32x4 acc[16];
#pragma unroll
  for (int f = 0; f < 16; ++f) acc[f] = (f32x4){0.f, 0.f, 0.f, 0.f};

#pragma unroll
  for (int s = 0; s < 4; ++s) {
    const int kb = s * 64 + kgrp * 16;
    const short8 a8 = *(const short8*)(inA_c + arow * 256 + (kb ^ ((arow & 7) << 4)));
#pragma unroll
    for (int f = 0; f < 16; ++f) {
      const int n = f * 16 + rlo;
      const short8 b8 = *(const short8*)(Wt_c + n * 256 + (kb ^ ((n & 7) << 4)));
      acc[f] = __builtin_amdgcn_mfma_f32_16x16x32_bf16(a8, b8, acc[f], 0, 0, 0);
    }
  }

  const int mg = m0g + wv * 16 + kgrp * 4;
#pragma unroll
  for (int f = 0; f < 8; ++f) {
    const int col = f * 16 + rlo;
#pragma unroll
    for (int r = 0; r < 4; ++r)
      Z[(size_t)(mg + r) * FDIM + col] = acc[f][r];
  }
  const int H = mg >> 7, ch = (mg >> 3) & 15, kin0 = mg & 7;
#pragma unroll
  for (int f = 8; f < 16; ++f) {
    const int c = f * 16 + rlo - 128;
    ushort4v u;
#pragma unroll
    for (int r = 0; r < 4; ++r) u[r] = f2bf(acc[f][r]);
    *(ushort4v*)(Yt + (size_t)H * 16384 + (size_t)(ch * 128 + c) * 8 + kin0) = u;
  }
}

// ---------------------------------------------------------------------------
// Kernel 2: out = adj @ Y + Z.  256 blocks x 512 thr (8 waves: 4M x 2N).
// ---------------------------------------------------------------------------

#define VMCNT(n) do { asm volatile("s_waitcnt vmcnt(" #n ")" ::: "memory");        \
                      __builtin_amdgcn_sched_barrier(0); } while (0)
#define LGKM0()  do { asm volatile("s_waitcnt lgkmcnt(0)" ::: "memory");           \
                      __builtin_amdgcn_sched_barrier(0); } while (0)
#define BAR()    do { __builtin_amdgcn_s_barrier();                                \
                      __builtin_amdgcn_sched_barrier(0); } while (0)
#define SCHED()  __builtin_amdgcn_sched_barrier(0)

// 8 asm loads: thread covers 1KB of its adj row for A-iter ka (regs untracked by
// compiler waitcnt pass -> our counted vmcnt owns them; rule 18 sched_barriers).
#define ALOAD(ka)                                                                  \
  { const char* _p = abase + (size_t)(ka) * 1024;                                  \
    asm volatile("global_load_dwordx4 %0, %1, off"            : "=v"(ar[0]) : "v"(_p)); \
    asm volatile("global_load_dwordx4 %0, %1, off offset:16"  : "=v"(ar[1]) : "v"(_p)); \
    asm volatile("global_load_dwordx4 %0, %1, off offset:256" : "=v"(ar[2]) : "v"(_p)); \
    asm volatile("global_load_dwordx4 %0, %1, off offset:272" : "=v"(ar[3]) : "v"(_p)); \
    asm volatile("global_load_dwordx4 %0, %1, off offset:512" : "=v"(ar[4]) : "v"(_p)); \
    asm volatile("global_load_dwordx4 %0, %1, off offset:528" : "=v"(ar[5]) : "v"(_p)); \
    asm volatile("global_load_dwordx4 %0, %1, off offset:768" : "=v"(ar[6]) : "v"(_p)); \
    asm volatile("global_load_dwordx4 %0, %1, off offset:784" : "=v"(ar[7]) : "v"(_p)); \
    SCHED(); }

// cvt fp32->bf16 and write 4 b128 chunks (conflict-free: 2 lanes/bank/quarter-wave)
#define ACVT_WRITE(buf)                                                            \
  { char* _aw = (char*)lds + (size_t)(buf) * 32768 + srow * 512;                   \
    _Pragma("unroll")                                                              \
    for (int _j = 0; _j < 4; ++_j) {                                               \
      bf16x8 _v;                                                                   \
      _Pragma("unroll")                                                            \
      for (int _i = 0; _i < 4; ++_i) {                                             \
        _v[_i]     = (__bf16)ar[2 * _j][_i];                                       \
        _v[_i + 4] = (__bf16)ar[2 * _j + 1][_i];                                   \
      }                                                                            \
      *(short8*)(_aw + (((_j * 8 + sj) ^ (srow & 7)) * 16)) =                      \
          __builtin_bit_cast(short8, _v);                                          \
    }                                                                              \
    SCHED(); }

// B sub-tile t (BK=128) -> Bbuf[b] via global_load_lds (4 ops/wave, linear)
#define BSTAGE(b, t)                                                               \
  { const unsigned short* _bs = Yt + (size_t)(t) * 16384;                          \
    char* _bd = (char*)lds + 65536 + (size_t)(b) * 32768;                          \
    _Pragma("unroll")                                                              \
    for (int _i = 0; _i < 4; ++_i) {                                               \
      const int _q = wv * 4 + _i;                                                  \
      __builtin_amdgcn_global_load_lds(                                            \
          (const __attribute__((address_space(1))) void*)(_bs + _q * 512 + lane * 8), \
          (__attribute__((address_space(3))) void*)(_bd + _q * 1024),              \
          16, 0, 0);                                                               \
    }                                                                              \
    SCHED(); }

// one BK=128 sub-tile of MFMA: A from bf16 LDS (1 b128/k-step), B from LDS
#define CHALF(abuf, sub, bbuf)                                                     \
  { const char* _Ap = (const char*)lds + (size_t)(abuf) * 32768 + arow_b;          \
    const char* _Bp = (const char*)lds + 65536 + (size_t)(bbuf) * 32768;           \
    _Pragma("unroll")                                                              \
    for (int _s = 0; _s < 4; ++_s) {                                               \
      const int _c = (sub) * 16 + _s * 4 + kgrp;                                   \
      const short8 _a8 = *(const short8*)(_Ap + ((_c ^ aswz) * 16));               \
      _Pragma("unroll")                                                            \
      for (int _f = 0; _f < 4; ++_f) {                                             \
        const int _n = nh * 64 + _f * 16 + rlo;                                    \
        const short8 _b8 = *(const short8*)(_Bp + (size_t)((_s * 4 + kgrp) * 128 + _n) * 16); \
        acc[_f] = __builtin_amdgcn_mfma_f32_16x16x32_bf16(_a8, _b8, acc[_f], 0, 0, 0); \
      }                                                                            \
    } }

__global__ __launch_bounds__(512, 1)
void gcn_main(const float* __restrict__ adj, const unsigned short* __restrict__ Yt,
              const float* __restrict__ Z, float* __restrict__ out)
{
  // [0,64K): A bf16, 2 bufs x (64 rows x 512B), XOR-swizzled chunks
  // [64K,160K): B bf16, 3 bufs x 32KB, pre-tiled layout
  __shared__ __align__(16) unsigned char lds[163840];

  const int tid  = threadIdx.x;
  const int lane = tid & 63;
  const int wv   = tid >> 6;     // 0..7
  const int rg   = wv >> 1;      // 16-row strip (0..3)
  const int nh   = wv & 1;       // 64-col half
  const int m0   = blockIdx.x * 64;
  const int rlo  = lane & 15;
  const int kgrp = lane >> 4;    // 0..3

  // A staging map: thread -> row srow, chunk-octant sj (1KB/row, v1 map)
  const int srow = tid >> 3;     // 0..63
  const int sj   = tid & 7;
  const char* abase = (const char*)(adj + (size_t)(m0 + srow) * NROWS) + sj * 32;

  // A compute-read map
  const int arow_b = (rg * 16 + rlo) * 512;
  const int aswz   = rlo & 7;

  f32x4 acc[4];
#pragma unroll
  for (int f = 0; f < 4; ++f) acc[f] = (f32x4){0.f, 0.f, 0.f, 0.f};

  f32x4 ar[8];   // in-flight A registers (32 VGPR)

  // ---- prologue ----
  ALOAD(0);                      // A(0) -> regs          [A8]
  BSTAGE(0, 0);                  //                        [A8 B4]
  BSTAGE(1, 1);                  //                        [A8 B4 B4]
  VMCNT(8);                      // force A(0) regs
  ACVT_WRITE(0);                 // Abuf0 <- A(0) bf16
  ALOAD(1);                      //                        [B4 B4 A8]
  VMCNT(12);                     // force B(0)             [B4 A8]
  LGKM0();                       // A-writes drained
  BAR();                         // Abuf0 + Bbuf0 visible

  // ---- iter 0 (peeled: A(1) already issued in prologue) ----
  BSTAGE(2, 2);                  //                        [B4(1) A8(1) B4(2)]
  CHALF(0, 0, 0);
  VMCNT(12);                     // force B(1)             [A8 B4]
  BAR();
  BSTAGE(0, 3);                  //                        [A8 B4(2) B4(3)]
  CHALF(0, 1, 1);
  VMCNT(8);                      // force A(1) regs        [B4 B4]
  ACVT_WRITE(1);                 // Abuf1 <- A(1)
  VMCNT(4);                      // force B(2)             [B4(3)]
  LGKM0();
  BAR();

  // ---- steady: kt = 1..62.  Invariant at entry: in-flight = B4(2kt+1);
  //      Abuf[kt&1] ready; B(2kt) forced; Bbuf[(2kt)%3] visible. ----
  int bA = 2;                    // (2*kt)%3 for kt=1
  for (int kt = 1; kt <= NTA - 2; ++kt) {
    const int abufC = kt & 1;
    const int bS0   = bA >= 1 ? bA - 1 : bA + 2;     // (2kt+2)%3
    const int bS1   = bA;                            // (2kt+3)%3 == (2kt)%3
    const int bC1   = bA < 2 ? bA + 1 : 0;           // (2kt+1)%3
    // even sub (t=2kt)
    ALOAD(kt + 1);               //                        [B4(2kt+1) A8 ]
    BSTAGE(bS0, 2 * kt + 2);     //                        [B4 A8 B4]
    CHALF(abufC, 0, bA);
    VMCNT(12);                   // force B(2kt+1)         [A8 B4]
    BAR();
    // odd sub (t=2kt+1)
    BSTAGE(bS1, 2 * kt + 3);     //                        [A8 B4(2kt+2) B4(2kt+3)]
    CHALF(abufC, 1, bC1);
    VMCNT(8);                    // force A(kt+1) regs     [B4 B4]
    ACVT_WRITE(abufC ^ 1);       // Abuf[(kt+1)&1] (last read 2 barriers ago)
    VMCNT(4);                    // force B(2kt+2)         [B4(2kt+3)]
    LGKM0();
    BAR();
    bA = bS0;                    // (2(kt+1))%3
  }

  // ---- kt = 63 (drain; entry in-flight: B4(127), bA = (126)%3 = 0) ----
  CHALF(1, 0, 0);
  VMCNT(0);                      // force B(127)
  BAR();
  CHALF(1, 1, 1);

  // epilogue: out = acc + Z.  C/D: row=(lane>>4)*4+reg, col=lane&15
  const int rowb = m0 + rg * 16 + (lane >> 4) * 4;
#pragma unroll
  for (int f = 0; f < 4; ++f) {
    const int col = nh * 64 + f * 16 + rlo;
#pragma unroll
    for (int r = 0; r < 4; ++r) {
      const size_t idx = (size_t)(rowb + r) * FDIM + col;
      out[idx] = acc[f][r] + Z[idx];
    }
  }
}

extern "C" void kernel_launch(void* const* d_in, const int* in_sizes, int n_in,
                              void* d_out, int out_size, void* d_ws, size_t ws_size,
                              hipStream_t stream) {
  const float* input  = (const float*)d_in[0];
  const float* adj    = (const float*)d_in[1];
  const float* weight = (const float*)d_in[2];
  float* out = (float*)d_out;

  unsigned short* Yt = (unsigned short*)d_ws;                           // 4MB bf16
  float* Z = (float*)((char*)d_ws + (size_t)NROWS * FDIM * 2);          // 8MB fp32

  gcn_prep<<<256, 256, 0, stream>>>(input, weight, Yt, Z);
  gcn_main<<<256, 512, 0, stream>>>(adj, Yt, Z, out);
}

// Round 7
// 206.436 us; speedup vs baseline: 1.0670x; 1.0670x over previous
//
#include <hip/hip_runtime.h>

// GraphConvolution: out = input @ W_self + (adj @ input) @ W_agg
//                       = adj @ (input @ W_agg) + input @ W_self   [associativity]
// Heavy op: adj(16384x16384 fp32, 1.07GB) @ Y(16384x128 bf16) -> memory-bound.
//
// main r7: BM=64 BN=128 BK=128, 256 blocks x 512 thr (8 waves: 4M x 2N).
//  TRIPLE-buffered A (bf16, reg-staged w/ r5's 2rowx512B load pattern, cvt once)
//  + TRIPLE-buffered B (global_load_lds, pre-tiled Yt) -> ONE barrier per iter.
//  LDS = 48KB A + 96KB B = 144KB. Single vmcnt(8) per iter (never 0 in loop).
//  A loads carry nt (one-shot stream); Yt stays L2-cached.
// prep (r5, unchanged): MFMA, Z fp32 + Y bf16 pre-tiled.
//
// ws: [0,4MB) Yt bf16 pre-tiled in 128-row tiles: elem = H*16384 + (ch*128+n)*8 + kin,
//     H=m>>7, ch=(m>>3)&15, kin=m&7.   [4MB,12MB) Z fp32 row-major.

#define NROWS 16384
#define FDIM  128
#define NT2   128          // K tiles of 128

typedef __attribute__((ext_vector_type(4))) float f32x4;
typedef __attribute__((ext_vector_type(8))) short short8;
typedef __attribute__((ext_vector_type(8))) __bf16 bf16x8;
typedef __attribute__((ext_vector_type(4))) unsigned short ushort4v;

static __device__ __forceinline__ unsigned short f2bf(float f) {
  union { __bf16 b; unsigned short u; } cvt;
  cvt.b = (__bf16)f;   // RNE fptrunc
  return cvt.u;
}

// ---------------------------------------------------------------------------
// Kernel 1 (MFMA): Z = input @ W_self (fp32), Y = input @ W_agg (bf16, tiled).
// ---------------------------------------------------------------------------
__global__ __launch_bounds__(256, 2)
void gcn_prep(const float* __restrict__ input, const float* __restrict__ weight,
              unsigned short* __restrict__ Yt, float* __restrict__ Z)
{
  __shared__ __align__(16) unsigned short inA[8192];    // 16KB
  __shared__ __align__(16) unsigned short Wt[32768];    // 64KB
  char* inA_c = (char*)inA;
  char* Wt_c  = (char*)Wt;

  const int tid  = threadIdx.x;
  const int lane = tid & 63;
  const int wv   = tid >> 6;     // 0..3
  const int m0g  = blockIdx.x * 64;

#pragma unroll
  for (int p = 0; p < 8; ++p) {
    const int idx4 = tid + p * 256;
    const int row  = idx4 >> 5;
    const int k0   = (idx4 & 31) * 4;
    const f32x4 v  = *(const f32x4*)(input + (size_t)(m0g + row) * FDIM + k0);
    ushort4v u;
#pragma unroll
    for (int i = 0; i < 4; ++i) u[i] = f2bf(v[i]);
    *(ushort4v*)(inA_c + row * 256 + ((k0 * 2) ^ ((row & 7) << 4))) = u;
  }
#pragma unroll
  for (int p = 0; p < 32; ++p) {
    const int e4   = tid + p * 256;
    const int krow = e4 >> 5;
    const int n0   = (e4 & 31) * 4;
    const f32x4 v  = *(const f32x4*)(weight + (size_t)krow * FDIM + n0);
    const int k  = krow & 127;
    const int nb = (krow >> 7) * 128;
#pragma unroll
    for (int i = 0; i < 4; ++i) {
      const int n = nb + n0 + i;
      *(unsigned short*)(Wt_c + n * 256 + ((k * 2) ^ ((n & 7) << 4))) = f2bf(v[i]);
    }
  }
  __syncthreads();

  const int rlo  = lane & 15;
  const int kgrp = lane >> 4;
  const int arow = wv * 16 + rlo;

  f32x4 acc[16];
#pragma unroll
  for (int f = 0; f < 16; ++f) acc[f] = (f32x4){0.f, 0.f, 0.f, 0.f};

#pragma unroll
  for (int s = 0; s < 4; ++s) {
    const int kb = s * 64 + kgrp * 16;
    const short8 a8 = *(const short8*)(inA_c + arow * 256 + (kb ^ ((arow & 7) << 4)));
#pragma unroll
    for (int f = 0; f < 16; ++f) {
      const int n = f * 16 + rlo;
      const short8 b8 = *(const short8*)(Wt_c + n * 256 + (kb ^ ((n & 7) << 4)));
      acc[f] = __builtin_amdgcn_mfma_f32_16x16x32_bf16(a8, b8, acc[f], 0, 0, 0);
    }
  }

  const int mg = m0g + wv * 16 + kgrp * 4;
#pragma unroll
  for (int f = 0; f < 8; ++f) {
    const int col = f * 16 + rlo;
#pragma unroll
    for (int r = 0; r < 4; ++r)
      Z[(size_t)(mg + r) * FDIM + col] = acc[f][r];
  }
  const int H = mg >> 7, ch = (mg >> 3) & 15, kin0 = mg & 7;
#pragma unroll
  for (int f = 8; f < 16; ++f) {
    const int c = f * 16 + rlo - 128;
    ushort4v u;
#pragma unroll
    for (int r = 0; r < 4; ++r) u[r] = f2bf(acc[f][r]);
    *(ushort4v*)(Yt + (size_t)H * 16384 + (size_t)(ch * 128 + c) * 8 + kin0) = u;
  }
}

// ---------------------------------------------------------------------------
// Kernel 2: out = adj @ Y + Z.  256 blocks x 512 thr.
// LDS: [0,48K) A bf16 3x16KB (XOR-swizzled 16B chunks);
//      [48K,144K) B bf16 3x32KB (pre-tiled Yt layout).
// ---------------------------------------------------------------------------

#define VMCNT(n) do { asm volatile("s_waitcnt vmcnt(" #n ")" ::: "memory");        \
                      __builtin_amdgcn_sched_barrier(0); } while (0)
#define LGKM0()  do { asm volatile("s_waitcnt lgkmcnt(0)" ::: "memory");           \
                      __builtin_amdgcn_sched_barrier(0); } while (0)
#define BAR()    do { __builtin_amdgcn_s_barrier();                                \
                      __builtin_amdgcn_sched_barrier(0); } while (0)
#define SCHED()  __builtin_amdgcn_sched_barrier(0)

// A(ka) -> register bank (4 x f32x4). r5's proven pattern: per instr,
// 2 rows x 512B contiguous (32 lanes/row). nt: one-shot stream.
#define ALOADR(BANK, ka)                                                           \
  { const long _o = (long)(ka) * 512;                                              \
    asm volatile("global_load_dwordx4 %0, %1, off nt" : "=v"(BANK[0]) : "v"(pA0 + _o)); \
    asm volatile("global_load_dwordx4 %0, %1, off nt" : "=v"(BANK[1]) : "v"(pA1 + _o)); \
    asm volatile("global_load_dwordx4 %0, %1, off nt" : "=v"(BANK[2]) : "v"(pA2 + _o)); \
    asm volatile("global_load_dwordx4 %0, %1, off nt" : "=v"(BANK[3]) : "v"(pA3 + _o)); \
    SCHED(); }

// cvt bank -> bf16, ds_write 4 x b64 into Abuf at aoff (swizzled; 2-way = free)
#define ACVT_WRITE(BANK, aoff)                                                     \
  { _Pragma("unroll")                                                              \
    for (int _i = 0; _i < 4; ++_i) {                                               \
      ushort4v _u;                                                                 \
      _Pragma("unroll")                                                            \
      for (int _j = 0; _j < 4; ++_j) _u[_j] = f2bf(BANK[_i][_j]);                  \
      *(ushort4v*)(lds + (aoff) + awo[_i]) = _u;                                   \
    }                                                                              \
    SCHED(); }

// B tile t (BK=128, 32KB) -> Bbuf at boff via global_load_lds (4 ops/wave)
#define BSTAGE(boff, t)                                                            \
  { const unsigned short* _bs = Yt + (size_t)(t) * 16384;                          \
    _Pragma("unroll")                                                              \
    for (int _i = 0; _i < 4; ++_i) {                                               \
      const int _q = wv * 4 + _i;                                                  \
      __builtin_amdgcn_global_load_lds(                                            \
          (const __attribute__((address_space(1))) void*)(_bs + _q * 512 + lane * 8), \
          (__attribute__((address_space(3))) void*)(lds + (boff) + _q * 1024),     \
          16, 0, 0);                                                               \
    }                                                                              \
    SCHED(); }

// one BK=128 tile of MFMA: A bf16 from Abuf(aoff), B from Bbuf(boff)
#define CTILE(aoff, boff)                                                          \
  { const char* _Ap = (const char*)lds + (aoff) + arow2;                           \
    const char* _Bp = (const char*)lds + (boff);                                   \
    _Pragma("unroll")                                                              \
    for (int _s = 0; _s < 4; ++_s) {                                               \
      const int _c = _s * 4 + kgrp;                                                \
      const short8 _a8 = *(const short8*)(_Ap + ((_c ^ aswz) * 16));               \
      _Pragma("unroll")                                                            \
      for (int _f = 0; _f < 4; ++_f) {                                             \
        const int _n = nh * 64 + _f * 16 + rlo;                                    \
        const short8 _b8 = *(const short8*)(_Bp + (size_t)(_c * 128 + _n) * 16);   \
        acc[_f] = __builtin_amdgcn_mfma_f32_16x16x32_bf16(_a8, _b8, acc[_f], 0, 0, 0); \
      }                                                                            \
    } }

#define ABUF(b) ((size_t)(b) * 16384)
#define BBUF(b) (49152 + (size_t)(b) * 32768)

__global__ __launch_bounds__(512, 1)
void gcn_main(const float* __restrict__ adj, const unsigned short* __restrict__ Yt,
              const float* __restrict__ Z, float* __restrict__ out)
{
  __shared__ __align__(16) char lds[147456];   // 144KB

  const int tid  = threadIdx.x;
  const int lane = tid & 63;
  const int wv   = tid >> 6;     // 0..7
  const int rg   = wv >> 1;      // 16-row strip (0..3)
  const int nh   = wv & 1;       // 64-col half
  const int m0   = blockIdx.x * 64;
  const int rlo  = lane & 15;
  const int kgrp = lane >> 4;    // 0..3

  // A stage map (thread -> 4 loads): instr i covers rows 2*(wv*4+i)+{0,1}
  const char* pA0;
  const char* pA1;
  const char* pA2;
  const char* pA3;
  int awo[4];
  {
#pragma unroll
    for (int i = 0; i < 4; ++i) {
      const int row_g = 2 * (wv * 4 + i) + (lane >> 5);
      const int j     = (lane & 31) ^ (row_g & 7);
      const char* p = (const char*)(adj + (size_t)(m0 + row_g) * NROWS + (size_t)j * 4);
      if (i == 0) pA0 = p; else if (i == 1) pA1 = p; else if (i == 2) pA2 = p; else pA3 = p;
      // bf16 write: slot j (8B) at chunk (j>>1)^(row&7), half j&1
      awo[i] = row_g * 256 + (((j >> 1) ^ (row_g & 7)) << 4) + ((j & 1) << 3);
    }
  }

  // compute-read maps
  const int arow2 = (rg * 16 + rlo) * 256;   // A bf16 row byte base
  const int aswz  = rlo & 7;

  f32x4 acc[4];
#pragma unroll
  for (int f = 0; f < 4; ++f) acc[f] = (f32x4){0.f, 0.f, 0.f, 0.f};

  f32x4 arA[4], arB[4];   // A in-flight register banks (A(ka) -> bank[ka&1])

  // ---- prologue: establish invariant for t=0 ----
  ALOADR(arA, 0);                //                         [A4(0)]
  BSTAGE(BBUF(0), 0);            //                         [A4(0) B4(0)]
  ALOADR(arB, 1);                //                         [A4(0) B4(0) A4(1)]
  BSTAGE(BBUF(1), 1);            //                         [+B4(1)] = 16
  VMCNT(8);                      // force A(0) regs + B(0)  [A4(1) B4(1)]
  ACVT_WRITE(arA, ABUF(0));      // Abuf0 <- A(0) bf16
  LGKM0();
  BAR();                         // publish Abuf0, Bbuf0

  // ---- steady: t = 0..125 (2x unrolled: even uses arA-load/arB-cvt) ----
  // invariant at entry of iter t: outstanding [A4(t+1) B4(t+1)];
  // Abuf[t%3], Bbuf[t%3] published; A(t+1) in flight -> bank[(t+1)&1].
  int bc = 0;                    // t % 3
  for (int tp = 0; tp < 63; ++tp) {
    const int t0 = 2 * tp;
    {
      const int bs = bc == 0 ? 2 : bc - 1;     // (t+2)%3
      const int bw = bc == 2 ? 0 : bc + 1;     // (t+1)%3
      ALOADR(arA, t0 + 2);       // A(t+2)->bank0           [A4(t+1) B4(t+1) A4(t+2)]
      BSTAGE(BBUF(bs), t0 + 2);  //                         [+B4(t+2)] = 16
      CTILE(ABUF(bc), BBUF(bc));
      VMCNT(8);                  // force A(t+1)+B(t+1)     [A4(t+2) B4(t+2)]
      ACVT_WRITE(arB, ABUF(bw)); // Abuf[(t+1)%3] <- A(t+1)
      LGKM0();
      BAR();
      bc = bw;
    }
    {
      const int t1 = t0 + 1;
      const int bs = bc == 0 ? 2 : bc - 1;
      const int bw = bc == 2 ? 0 : bc + 1;
      ALOADR(arB, t1 + 2);       // A(t+2)->bank1
      BSTAGE(BBUF(bs), t1 + 2);
      CTILE(ABUF(bc), BBUF(bc));
      VMCNT(8);
      ACVT_WRITE(arA, ABUF(bw));
      LGKM0();
      BAR();
      bc = bw;
    }
  }

  // ---- t = 126 (drain: nothing left to issue; entry [A4(127) B4(127)], bc=0) ----
  CTILE(ABUF(0), BBUF(0));
  VMCNT(0);                      // force A(127) regs + B(127)
  ACVT_WRITE(arB, ABUF(1));      // Abuf1 <- A(127)
  LGKM0();
  BAR();
  // ---- t = 127 ----
  CTILE(ABUF(1), BBUF(1));

  // epilogue: out = acc + Z.  C/D: row=(lane>>4)*4+reg, col=lane&15
  const int rowb = m0 + rg * 16 + (lane >> 4) * 4;
#pragma unroll
  for (int f = 0; f < 4; ++f) {
    const int col = nh * 64 + f * 16 + rlo;
#pragma unroll
    for (int r = 0; r < 4; ++r) {
      const size_t idx = (size_t)(rowb + r) * FDIM + col;
      out[idx] = acc[f][r] + Z[idx];
    }
  }
}

extern "C" void kernel_launch(void* const* d_in, const int* in_sizes, int n_in,
                              void* d_out, int out_size, void* d_ws, size_t ws_size,
                              hipStream_t stream) {
  const float* input  = (const float*)d_in[0];
  const float* adj    = (const float*)d_in[1];
  const float* weight = (const float*)d_in[2];
  float* out = (float*)d_out;

  unsigned short* Yt = (unsigned short*)d_ws;                           // 4MB bf16
  float* Z = (float*)((char*)d_ws + (size_t)NROWS * FDIM * 2);          // 8MB fp32

  gcn_prep<<<256, 256, 0, stream>>>(input, weight, Yt, Z);
  gcn_main<<<256, 512, 0, stream>>>(adj, Yt, Z, out);
}

// Round 8
// 187.882 us; speedup vs baseline: 1.1724x; 1.0988x over previous
//
#include <hip/hip_runtime.h>

// GraphConvolution: out = input @ W_self + (adj @ input) @ W_agg
//                       = adj @ (input @ W_agg) + input @ W_self   [associativity]
//                       = [adj | input] @ [Y ; W_self]             [K-extension]
// Heavy op: adj(16384x16384 fp32, 1.07GB) streamed once -> memory-bound,
// floor ~168us @6.4TB/s.
//
// main (r8): r5's proven structure + 1 extra K-tile (input @ W_self) -> no Z array.
//  BM=64 BK=128, 256 blocks x 512 thr (8 waves: 4M x 2N), depth-2 LDS pipeline,
//  counted vmcnt(8), NT on adj stream, rule-21 XOR-swizzled A, 129 tiles.
// prep (r8): MFMA, Y = input @ W_agg only (bf16 pre-tiled); W_self tiled as
//  Yt tile #128 (1 elem/thread across blocks).
//
// ws: [0, 4.03MB) Yt bf16 pre-tiled 128-row tiles: elem = H*16384 + (ch*128+n)*8 + kin,
//     H=m>>7, ch=(m>>3)&15, kin=m&7.  Tile H=128 holds W_self (k=ch*8+kin).

#define NROWS 16384
#define FDIM  128
#define NT3   129          // 128 adj K-tiles + 1 input K-tile

typedef __attribute__((ext_vector_type(4))) float f32x4;
typedef __attribute__((ext_vector_type(8))) short short8;
typedef __attribute__((ext_vector_type(8))) __bf16 bf16x8;
typedef __attribute__((ext_vector_type(4))) unsigned short ushort4v;

static __device__ __forceinline__ unsigned short f2bf(float f) {
  union { __bf16 b; unsigned short u; } cvt;
  cvt.b = (__bf16)f;   // RNE fptrunc
  return cvt.u;
}

// ---------------------------------------------------------------------------
// Kernel 1 (MFMA): Y = input @ W_agg (bf16, pre-tiled). Also writes W_self
// as pre-tiled Yt tile #128 (1 elem/thread, 64 elems/block).
// 256 blocks x 256 thr (4 waves), 64 input rows/block.
// ---------------------------------------------------------------------------
__global__ __launch_bounds__(256, 2)
void gcn_prep(const float* __restrict__ input, const float* __restrict__ weight,
              unsigned short* __restrict__ Yt)
{
  __shared__ __align__(16) unsigned short inA[8192];    // 16KB  [64 rows][128 k]
  __shared__ __align__(16) unsigned short Wt[16384];    // 32KB  [128 n][128 k] (W_agg)
  char* inA_c = (char*)inA;
  char* Wt_c  = (char*)Wt;

  const int tid  = threadIdx.x;
  const int lane = tid & 63;
  const int wv   = tid >> 6;     // 0..3
  const int m0g  = blockIdx.x * 64;

  // W_self -> Yt tile #128 (cooperative, 64 elems per block)
  if (tid < 64) {
    const int e = blockIdx.x * 64 + tid;     // [0,16384)
    const int k = e >> 7, n = e & 127;
    Yt[(size_t)128 * 16384 + (size_t)((k >> 3) * 128 + n) * 8 + (k & 7)] =
        f2bf(weight[(size_t)k * FDIM + n]);
  }

  // stage input rows [m0g, m0g+64) as bf16, swizzled
#pragma unroll
  for (int p = 0; p < 8; ++p) {
    const int idx4 = tid + p * 256;          // [0,2048)
    const int row  = idx4 >> 5;
    const int k0   = (idx4 & 31) * 4;
    const f32x4 v  = *(const f32x4*)(input + (size_t)(m0g + row) * FDIM + k0);
    ushort4v u;
#pragma unroll
    for (int i = 0; i < 4; ++i) u[i] = f2bf(v[i]);
    *(ushort4v*)(inA_c + row * 256 + ((k0 * 2) ^ ((row & 7) << 4))) = u;
  }
  // stage W_agg transposed: Wt[n][k] = weight[128+k][n], swizzled
#pragma unroll
  for (int p = 0; p < 16; ++p) {
    const int e4   = tid + p * 256;          // [0,4096)
    const int krow = 128 + (e4 >> 5);        // 128..255
    const int n0   = (e4 & 31) * 4;
    const f32x4 v  = *(const f32x4*)(weight + (size_t)krow * FDIM + n0);
    const int k = krow & 127;
#pragma unroll
    for (int i = 0; i < 4; ++i) {
      const int n = n0 + i;
      *(unsigned short*)(Wt_c + n * 256 + ((k * 2) ^ ((n & 7) << 4))) = f2bf(v[i]);
    }
  }
  __syncthreads();

  const int rlo  = lane & 15;
  const int kgrp = lane >> 4;
  const int arow = wv * 16 + rlo;

  f32x4 acc[8];
#pragma unroll
  for (int f = 0; f < 8; ++f) acc[f] = (f32x4){0.f, 0.f, 0.f, 0.f};

#pragma unroll
  for (int s = 0; s < 4; ++s) {
    const int kb = s * 64 + kgrp * 16;       // byte offset of k-range
    const short8 a8 = *(const short8*)(inA_c + arow * 256 + (kb ^ ((arow & 7) << 4)));
#pragma unroll
    for (int f = 0; f < 8; ++f) {
      const int n = f * 16 + rlo;
      const short8 b8 = *(const short8*)(Wt_c + n * 256 + (kb ^ ((n & 7) << 4)));
      acc[f] = __builtin_amdgcn_mfma_f32_16x16x32_bf16(a8, b8, acc[f], 0, 0, 0);
    }
  }

  // Y epilogue: bf16 tiled; kin innermost -> 4 rows pack into 8B
  const int mg = m0g + wv * 16 + kgrp * 4;
  const int H = mg >> 7, ch = (mg >> 3) & 15, kin0 = mg & 7;   // kin0 in {0,4}
#pragma unroll
  for (int f = 0; f < 8; ++f) {
    const int c = f * 16 + rlo;
    ushort4v u;
#pragma unroll
    for (int r = 0; r < 4; ++r) u[r] = f2bf(acc[f][r]);
    *(ushort4v*)(Yt + (size_t)H * 16384 + (size_t)(ch * 128 + c) * 8 + kin0) = u;
  }
}

// ---------------------------------------------------------------------------
// Kernel 2: out = [adj | input] @ [Y ; W_self].  BM=64 BN=128 BK=128.
// 256 blocks x 512 thr. 129 K-tiles; tile 128 sources A from `input`.
// ---------------------------------------------------------------------------
__global__ __launch_bounds__(512, 1)
void gcn_main(const float* __restrict__ adj, const float* __restrict__ input,
              const unsigned short* __restrict__ Yt, float* __restrict__ out)
{
  // per buffer: [0,32768) B bf16 tiled, [32768,65536) A fp32 swizzled (64 rows x 512B)
  __shared__ __align__(16) unsigned char lds[2][65536];

  const int tid  = threadIdx.x;
  const int lane = tid & 63;
  const int wv   = tid >> 6;     // 0..7
  const int rg   = wv >> 1;      // 16-row strip (0..3)
  const int nh   = wv & 1;       // 64-col half
  const int m0   = blockIdx.x * 64;
  const int rlo  = lane & 15;
  const int kgrp = lane >> 4;    // 0..3

  f32x4 acc[4];
#pragma unroll
  for (int f = 0; f < 4; ++f) acc[f] = (f32x4){0.f, 0.f, 0.f, 0.f};

  // B tile kt -> lds[buf][0..32K) via global_load_lds (linear, pre-tiled Yt)
  auto stageB = [&](int buf, int kt) {
    const unsigned short* bs = Yt + (size_t)kt * 16384;
#pragma unroll
    for (int i = 0; i < 4; ++i) {
      const int q = wv * 4 + i;                     // 32 chunks of 1KB
      __builtin_amdgcn_global_load_lds(
          (const __attribute__((address_space(1))) void*)(bs + q * 512 + lane * 8),
          (__attribute__((address_space(3))) void*)(&lds[buf][q * 1024]),
          16, 0, 0);
    }
  };
  // A tile (adj): 64 rows x 512B, source-XOR-swizzled, NT policy
  auto stageA = [&](int buf, int kt) {
#pragma unroll
    for (int i = 0; i < 4; ++i) {
      const int p     = wv * 4 + i;                 // row pair
      const int row_g = 2 * p + (lane >> 5);
      const int j     = (lane & 31) ^ (row_g & 7);
      const float* as = adj + (size_t)(m0 + row_g) * NROWS + (size_t)kt * 128 + j * 4;
      __builtin_amdgcn_global_load_lds(
          (const __attribute__((address_space(1))) void*)as,
          (__attribute__((address_space(3))) void*)(&lds[buf][32768 + p * 1024]),
          16, 0, 2 /* NT: one-shot stream, keep Yt in L2 */);
    }
  };
  // Final tile: A = input rows (contiguous 512B rows), B = W_self tile (#128)
  auto stageF = [&](int buf) {
    stageB(buf, 128);
#pragma unroll
    for (int i = 0; i < 4; ++i) {
      const int p     = wv * 4 + i;
      const int row_g = 2 * p + (lane >> 5);
      const int j     = (lane & 31) ^ (row_g & 7);
      const float* as = input + (size_t)(m0 + row_g) * FDIM + j * 4;
      __builtin_amdgcn_global_load_lds(
          (const __attribute__((address_space(1))) void*)as,
          (__attribute__((address_space(3))) void*)(&lds[buf][32768 + p * 1024]),
          16, 0, 0);
    }
  };

  // prologue: tiles 0,1 in flight (16 ops/wave)
  stageB(0, 0); stageA(0, 0);
  stageB(1, 1); stageA(1, 1);

  const int arow = (rg * 16 + rlo) * 512;   // byte offset of this lane's A row
  const int aswz = rlo & 7;

  for (int kt = 0; kt < NT3; ++kt) {
    if (kt < NT3 - 1) {
      asm volatile("s_waitcnt vmcnt(8)" ::: "memory");   // stage(kt) landed; kt+1 in flight
    } else {
      asm volatile("s_waitcnt vmcnt(0)" ::: "memory");
    }
    __builtin_amdgcn_sched_barrier(0);
    __builtin_amdgcn_s_barrier();                       // buf[kt&1] fully staged, all waves
    __builtin_amdgcn_sched_barrier(0);

    const int buf = kt & 1;
    const unsigned char* Bp = lds[buf];
    const unsigned char* Ap = Bp + 32768;

    // A frags: k-step s (K=32): k = s*32 + kgrp*8 + {0..7} -> chunks s*8+kgrp*2, +1
    short8 a8[4];
#pragma unroll
    for (int s = 0; s < 4; ++s) {
      const int c0 = s * 8 + kgrp * 2;
      const f32x4 lo = *(const f32x4*)(Ap + arow + ((c0    ) ^ aswz) * 16);
      const f32x4 hi = *(const f32x4*)(Ap + arow + ((c0 + 1) ^ aswz) * 16);
      bf16x8 av;
#pragma unroll
      for (int j = 0; j < 4; ++j) {
        av[j]     = (__bf16)lo[j];
        av[j + 4] = (__bf16)hi[j];
      }
      a8[s] = __builtin_bit_cast(short8, av);
    }

#pragma unroll
    for (int s = 0; s < 4; ++s) {
      const int ch = s * 4 + kgrp;
#pragma unroll
      for (int f = 0; f < 4; ++f) {
        const int n = nh * 64 + f * 16 + rlo;
        const short8 b8 = *(const short8*)(Bp + (size_t)(ch * 128 + n) * 16);
        acc[f] = __builtin_amdgcn_mfma_f32_16x16x32_bf16(a8[s], b8, acc[f], 0, 0, 0);
      }
    }

    __builtin_amdgcn_s_barrier();                       // all waves done reading buf
    __builtin_amdgcn_sched_barrier(0);
    if (kt + 2 < NT3) {                                 // overwrite freed buf
      if (kt + 2 == 128) stageF(buf);
      else { stageB(buf, kt + 2); stageA(buf, kt + 2); }
    }
  }

  // epilogue: out = acc (Z folded into K-tile 128).  C/D: row=(lane>>4)*4+reg, col=lane&15
  const int rowb = m0 + rg * 16 + (lane >> 4) * 4;
#pragma unroll
  for (int f = 0; f < 4; ++f) {
    const int col = nh * 64 + f * 16 + rlo;
#pragma unroll
    for (int r = 0; r < 4; ++r) {
      const size_t idx = (size_t)(rowb + r) * FDIM + col;
      out[idx] = acc[f][r];
    }
  }
}

extern "C" void kernel_launch(void* const* d_in, const int* in_sizes, int n_in,
                              void* d_out, int out_size, void* d_ws, size_t ws_size,
                              hipStream_t stream) {
  const float* input  = (const float*)d_in[0];
  const float* adj    = (const float*)d_in[1];
  const float* weight = (const float*)d_in[2];
  float* out = (float*)d_out;

  unsigned short* Yt = (unsigned short*)d_ws;   // (128+1) tiles x 32KB = 4.03MB bf16

  gcn_prep<<<256, 256, 0, stream>>>(input, weight, Yt);
  gcn_main<<<256, 512, 0, stream>>>(adj, input, Yt, out);
}